// Round 19
// baseline (5236.286 us; speedup 1.0000x reference)
//
#include <hip/hip_runtime.h>

typedef _Float16 f16x8 __attribute__((ext_vector_type(8)));
typedef float f32x4 __attribute__((ext_vector_type(4)));

#define LOG2E 1.44269504088896340736f
#define MELEM 16          // batch elems per block (1 M-tile of 16)
#define HS 72             // f16 stride of h LDS rows (16B-aligned, bank-spread)
#define INV2K 4.8828125e-4f   // 2^-11
#define SC2K  2048.0f         // 2^11

__device__ __forceinline__ float bpermf(int sa, float v) {
    return __builtin_bit_cast(float,
        __builtin_amdgcn_ds_bpermute(sa, __builtin_bit_cast(int, v)));
}

// barrier that waits ONLY on LDS (lgkm), not on in-flight global traj stores
#define LDS_BARRIER() asm volatile("s_waitcnt lgkmcnt(0)\n\ts_barrier" ::: "memory")

// R18 structure; launch_bounds min-waves=4 so the allocator packs the unified
// VGPR+AGPR state into a 128-reg/wave budget -> 4 waves/SIMD resident.
// (R8 precedent: (256,4) fit 64 arch + ~55 acc without spilling.)
__global__ __launch_bounds__(256, 4)
void gru_mfma_kernel(const float* __restrict__ z0,
                     const float* __restrict__ dtp,
                     const int* __restrict__ stepsp,
                     const float* __restrict__ Wih,
                     const float* __restrict__ Whh,
                     const float* __restrict__ bih,
                     const float* __restrict__ bhh,
                     const float* __restrict__ Whead,
                     const float* __restrict__ bhead,
                     float* __restrict__ out)
{
    // [pingpong][elem*HS + unit], plain fp16 h  (4608 B)
    __shared__ _Float16 hbuf[2][MELEM*HS];

    const int tid = threadIdx.x;
    const int w   = tid >> 6;       // wave 0..3 = unit group
    const int l   = tid & 63;
    const int c16 = l & 15;
    const int g   = l >> 4;         // 0..3
    const int unit = 16*w + c16;

    const float dtv = dtp[0];
    const int nsteps = stepsp[0];
    const size_t T3 = (size_t)(nsteps + 1) * 3;
    const long blk = blockIdx.x;

    // ---- B-fragments of W_hh: fp16 hi + 2^11-scaled lo, LOG2E-prescaled ----
    f16x8 WBh[3][2], WBl[3][2];
    #pragma unroll
    for (int gate = 0; gate < 3; ++gate) {
        const float gs = (gate == 2) ? 2.f*LOG2E : LOG2E;
        const float* row = Whh + (size_t)(gate*64 + unit) * 64;
        #pragma unroll
        for (int kk = 0; kk < 2; ++kk) {
            const float* p = row + 32*kk + 8*g;
            f16x8 bh_, bl_;
            #pragma unroll
            for (int j = 0; j < 8; ++j) {
                float x = gs * p[j];
                _Float16 hi = (_Float16)x;
                bh_[j] = hi;
                bl_[j] = (_Float16)((x - (float)hi) * SC2K);
            }
            WBh[gate][kk] = bh_;
            WBl[gate][kk] = bl_;
        }
    }
    // ---- head B-fragments in regs (cols >= 3 zero), plain scale ----
    f16x8 HBh[2], HBl[2];
    {
        f16x8 zf = {0,0,0,0,0,0,0,0};
        HBh[0]=zf; HBh[1]=zf; HBl[0]=zf; HBl[1]=zf;
        if (c16 < 3) {
            #pragma unroll
            for (int kk = 0; kk < 2; ++kk) {
                const float* p = Whead + (size_t)c16*64 + 32*kk + 8*g;
                f16x8 bh_, bl_;
                #pragma unroll
                for (int j = 0; j < 8; ++j) {
                    float x = p[j];
                    _Float16 hi = (_Float16)x;
                    bh_[j] = hi;
                    bl_[j] = (_Float16)((x - (float)hi) * SC2K);
                }
                HBh[kk] = bh_; HBl[kk] = bl_;
            }
        }
    }

    // ---- per-lane scalar weights / biases (prescaled) ----
    const float wir0 = LOG2E*Wih[(0*64+unit)*3+0], wir1 = LOG2E*Wih[(0*64+unit)*3+1], wir2 = LOG2E*Wih[(0*64+unit)*3+2];
    const float wiu0 = LOG2E*Wih[(1*64+unit)*3+0], wiu1 = LOG2E*Wih[(1*64+unit)*3+1], wiu2 = LOG2E*Wih[(1*64+unit)*3+2];
    const float win0 = 2.f*LOG2E*Wih[(2*64+unit)*3+0], win1 = 2.f*LOG2E*Wih[(2*64+unit)*3+1], win2 = 2.f*LOG2E*Wih[(2*64+unit)*3+2];
    const float br   = LOG2E*(bih[0*64+unit] + bhh[0*64+unit]);
    const float bu   = LOG2E*(bih[1*64+unit] + bhh[1*64+unit]);
    const float bin_ = 2.f*LOG2E*bih[2*64+unit];
    const float bhn  = 2.f*LOG2E*bhh[2*64+unit];
    float bhc = 0.f;
    if (c16 < 3) bhc = bhead[c16];

    // ---- z for the block's 16-elem tile, replicated across all lanes ----
    float zreg[4][3];
    #pragma unroll
    for (int r = 0; r < 4; ++r)
        #pragma unroll
        for (int c = 0; c < 3; ++c)
            zreg[r][c] = z0[(size_t)(blk*MELEM + 4*g + r)*3 + c];

    // ---- persistent traj cursors (designated: wave 0, c16<3) ----
    float* o0 = out; float* o1 = out; float* o2 = out; float* o3 = out;
    if (w == 0 && c16 < 3) {
        size_t e0 = (size_t)(blk*MELEM + 4*g);
        o0 = out + (e0+0)*T3 + c16;
        o1 = out + (e0+1)*T3 + c16;
        o2 = out + (e0+2)*T3 + c16;
        o3 = out + (e0+3)*T3 + c16;
    }
    // t=0 row
    #pragma unroll
    for (int c = 0; c < 3; ++c)
        if (w == 0 && c16 == c) {
            o0[0] = zreg[0][c]; o1[0] = zreg[1][c];
            o2[0] = zreg[2][c]; o3[0] = zreg[3][c];
        }
    if (w == 0 && c16 < 3) { o0 += 3; o1 += 3; o2 += 3; o3 += 3; }  // -> t=1

    // hoisted bpermute byte-addresses
    const int sa0 = (l & 48) << 2;
    const int sa1 = sa0 + 4;
    const int sa2 = sa0 + 8;

    // step-invariant LDS element offsets
    const int adA0 = c16*HS + 8*g;           // A-frag read row
    const int adW  = (4*g)*HS + unit;        // h write base (+ r*HS)

    // ---- zero h buffer 0 (h_0 = 0): 576 dwords ----
    {
        uint* hz = (uint*)&hbuf[0][0];
        for (int i = tid; i < (MELEM*HS)/2; i += 256) hz[i] = 0u;
    }

    float hC[4] = {0.f,0.f,0.f,0.f};

    __syncthreads();

#define GATE(GT, GR, BIAS) do {                                                  \
    f32x4 a1 = {BIAS,BIAS,BIAS,BIAS}, a2 = {0.f,0.f,0.f,0.f};                    \
    a1 = __builtin_amdgcn_mfma_f32_16x16x32_f16(FAh0, WBh[GT][0], a1, 0,0,0);    \
    a2 = __builtin_amdgcn_mfma_f32_16x16x32_f16(FAh0, WBl[GT][0], a2, 0,0,0);    \
    a1 = __builtin_amdgcn_mfma_f32_16x16x32_f16(FAh1, WBh[GT][1], a1, 0,0,0);    \
    a2 = __builtin_amdgcn_mfma_f32_16x16x32_f16(FAh1, WBl[GT][1], a2, 0,0,0);    \
    _Pragma("unroll")                                                            \
    for (int rr = 0; rr < 4; ++rr) GR[rr] = __builtin_fmaf(INV2K, a2[rr], a1[rr]); \
} while (0)

#define STEP(P, DOZ) do {                                                        \
    f16x8 FAh0 = *(const f16x8*)&hbuf[P][adA0];                                  \
    f16x8 FAh1 = *(const f16x8*)&hbuf[P][adA0 + 32];                             \
    if (DOZ) {                                                                   \
        f32x4 a = {bhc,bhc,bhc,bhc}, b = {0.f,0.f,0.f,0.f};                      \
        a = __builtin_amdgcn_mfma_f32_16x16x32_f16(FAh0, HBh[0], a, 0,0,0);      \
        a = __builtin_amdgcn_mfma_f32_16x16x32_f16(FAh1, HBh[1], a, 0,0,0);      \
        b = __builtin_amdgcn_mfma_f32_16x16x32_f16(FAh0, HBl[0], b, 0,0,0);      \
        b = __builtin_amdgcn_mfma_f32_16x16x32_f16(FAh1, HBl[1], b, 0,0,0);      \
        _Pragma("unroll")                                                        \
        for (int r = 0; r < 4; ++r) {                                            \
            float fv = __builtin_fmaf(INV2K, b[r], a[r]);                        \
            zreg[r][0] = __builtin_fmaf(dtv, bpermf(sa0, fv), zreg[r][0]);       \
            zreg[r][1] = __builtin_fmaf(dtv, bpermf(sa1, fv), zreg[r][1]);       \
            zreg[r][2] = __builtin_fmaf(dtv, bpermf(sa2, fv), zreg[r][2]);       \
        }                                                                        \
        _Pragma("unroll")                                                        \
        for (int c = 0; c < 3; ++c)                                              \
            if (w == 0 && c16 == c) {                                            \
                o0[0] = zreg[0][c]; o1[0] = zreg[1][c];                          \
                o2[0] = zreg[2][c]; o3[0] = zreg[3][c];                          \
            }                                                                    \
        if (w == 0 && c16 < 3) { o0 += 3; o1 += 3; o2 += 3; o3 += 3; }           \
    }                                                                            \
    f32x4 gr0, gr1, gr2;                                                         \
    GATE(0, gr0, br); GATE(1, gr1, bu); GATE(2, gr2, bhn);                       \
    _Pragma("unroll")                                                            \
    for (int r = 0; r < 4; ++r) {                                                \
        float z0v = zreg[r][0], z1v = zreg[r][1], z2v = zreg[r][2];              \
        float ar  = __builtin_fmaf(wir0, z0v, __builtin_fmaf(wir1, z1v,          \
                    __builtin_fmaf(wir2, z2v, gr0[r])));                         \
        float au  = __builtin_fmaf(wiu0, z0v, __builtin_fmaf(wiu1, z1v,          \
                    __builtin_fmaf(wiu2, z2v, gr1[r])));                         \
        float ain = __builtin_fmaf(win0, z0v, __builtin_fmaf(win1, z1v,          \
                    __builtin_fmaf(win2, z2v, bin_)));                           \
        float rg  = __builtin_amdgcn_rcpf(1.f + __builtin_amdgcn_exp2f(-ar));    \
        float ug_ = __builtin_amdgcn_rcpf(1.f + __builtin_amdgcn_exp2f(-au));    \
        float xs  = __builtin_fmaf(rg, gr2[r], ain);                             \
        float ng  = __builtin_fmaf(-2.f,                                         \
            __builtin_amdgcn_rcpf(1.f + __builtin_amdgcn_exp2f(xs)), 1.f);       \
        float hn  = __builtin_fmaf(ug_, hC[r] - ng, ng);                         \
        hC[r] = hn;                                                              \
        hbuf[(P)^1][adW + r*HS] = (_Float16)hn;                                  \
    }                                                                            \
    LDS_BARRIER();                                                               \
} while (0)

    // ---- main loop: peel t=0, then pairs (compile-time ping-pong) ----
    STEP(0, false);
    int t = 1;
    for (; t + 1 < nsteps; t += 2) {
        STEP(1, true);
        STEP(0, true);
    }
    if (t < nsteps) { STEP(1, true); ++t; }

    // ---- epilogue: z(nsteps) from head over h(nsteps) ----
    {
        const int P = nsteps & 1;
        f16x8 FAh0 = *(const f16x8*)&hbuf[P][adA0];
        f16x8 FAh1 = *(const f16x8*)&hbuf[P][adA0 + 32];
        f32x4 a = {bhc,bhc,bhc,bhc}, b = {0.f,0.f,0.f,0.f};
        a = __builtin_amdgcn_mfma_f32_16x16x32_f16(FAh0, HBh[0], a, 0,0,0);
        a = __builtin_amdgcn_mfma_f32_16x16x32_f16(FAh1, HBh[1], a, 0,0,0);
        b = __builtin_amdgcn_mfma_f32_16x16x32_f16(FAh0, HBl[0], b, 0,0,0);
        b = __builtin_amdgcn_mfma_f32_16x16x32_f16(FAh1, HBl[1], b, 0,0,0);
        #pragma unroll
        for (int r = 0; r < 4; ++r) {
            float fv = __builtin_fmaf(INV2K, b[r], a[r]);
            zreg[r][0] = __builtin_fmaf(dtv, bpermf(sa0, fv), zreg[r][0]);
            zreg[r][1] = __builtin_fmaf(dtv, bpermf(sa1, fv), zreg[r][1]);
            zreg[r][2] = __builtin_fmaf(dtv, bpermf(sa2, fv), zreg[r][2]);
        }
        #pragma unroll
        for (int c = 0; c < 3; ++c)
            if (w == 0 && c16 == c) {
                o0[0] = zreg[0][c]; o1[0] = zreg[1][c];
                o2[0] = zreg[2][c]; o3[0] = zreg[3][c];
            }
    }
#undef STEP
#undef GATE
}

extern "C" void kernel_launch(void* const* d_in, const int* in_sizes, int n_in,
                              void* d_out, int out_size, void* d_ws, size_t ws_size,
                              hipStream_t stream) {
    const float* z0    = (const float*)d_in[0];
    const float* dtp   = (const float*)d_in[1];
    const int*   steps = (const int*)  d_in[2];
    const float* Wih   = (const float*)d_in[3];
    const float* Whh   = (const float*)d_in[4];
    const float* bih   = (const float*)d_in[5];
    const float* bhh   = (const float*)d_in[6];
    const float* Whead = (const float*)d_in[7];
    const float* bhead = (const float*)d_in[8];
    float* out = (float*)d_out;

    const int B = in_sizes[0] / 3;          // 16384
    const int nblk = B / MELEM;             // 1024 blocks x 256 threads

    hipLaunchKernelGGL(gru_mfma_kernel, dim3(nblk), dim3(256), 0, stream,
                       z0, dtp, steps, Wih, Whh, bih, bhh, Whead, bhead, out);
}

// Round 20
// 2612.103 us; speedup vs baseline: 2.0046x; 2.0046x over previous
//
#include <hip/hip_runtime.h>

typedef _Float16 f16x8 __attribute__((ext_vector_type(8)));
typedef float f32x4 __attribute__((ext_vector_type(4)));

#define LOG2E 1.44269504088896340736f
#define MELEM 16          // batch elems per block (1 M-tile of 16)
#define HS 72             // f16 stride of h LDS rows (16B-aligned, bank-spread)

__device__ __forceinline__ float bpermf(int sa, float v) {
    return __builtin_bit_cast(float,
        __builtin_amdgcn_ds_bpermute(sa, __builtin_bit_cast(int, v)));
}

// barrier that waits ONLY on LDS (lgkm), not on in-flight global traj stores
#define LDS_BARRIER() asm volatile("s_waitcnt lgkmcnt(0)\n\ts_barrier" ::: "memory")

// R18 structure; ALL weights plain fp16 (no lo split). Measured basis: R18
// showed h-fp16 noise (~5e-4 rel) is invisible under the 0.0625 ref floor;
// weight-hi rounding adds same-order, sign-random noise -> z err ~1e-3.
__global__ __launch_bounds__(256, 2)
void gru_mfma_kernel(const float* __restrict__ z0,
                     const float* __restrict__ dtp,
                     const int* __restrict__ stepsp,
                     const float* __restrict__ Wih,
                     const float* __restrict__ Whh,
                     const float* __restrict__ bih,
                     const float* __restrict__ bhh,
                     const float* __restrict__ Whead,
                     const float* __restrict__ bhead,
                     float* __restrict__ out)
{
    // [pingpong][elem*HS + unit], plain fp16 h  (4608 B)
    __shared__ _Float16 hbuf[2][MELEM*HS];

    const int tid = threadIdx.x;
    const int w   = tid >> 6;       // wave 0..3 = unit group
    const int l   = tid & 63;
    const int c16 = l & 15;
    const int g   = l >> 4;         // 0..3
    const int unit = 16*w + c16;

    const float dtv = dtp[0];
    const int nsteps = stepsp[0];
    const size_t T3 = (size_t)(nsteps + 1) * 3;
    const long blk = blockIdx.x;

    // ---- B-fragments of W_hh: plain fp16, LOG2E-prescaled ----
    f16x8 WBh[3][2];
    #pragma unroll
    for (int gate = 0; gate < 3; ++gate) {
        const float gs = (gate == 2) ? 2.f*LOG2E : LOG2E;
        const float* row = Whh + (size_t)(gate*64 + unit) * 64;
        #pragma unroll
        for (int kk = 0; kk < 2; ++kk) {
            const float* p = row + 32*kk + 8*g;
            f16x8 bh_;
            #pragma unroll
            for (int j = 0; j < 8; ++j) bh_[j] = (_Float16)(gs * p[j]);
            WBh[gate][kk] = bh_;
        }
    }
    // ---- head B-fragments, plain fp16 (cols >= 3 zero) ----
    f16x8 HBh[2];
    {
        f16x8 zf = {0,0,0,0,0,0,0,0};
        HBh[0]=zf; HBh[1]=zf;
        if (c16 < 3) {
            #pragma unroll
            for (int kk = 0; kk < 2; ++kk) {
                const float* p = Whead + (size_t)c16*64 + 32*kk + 8*g;
                f16x8 bh_;
                #pragma unroll
                for (int j = 0; j < 8; ++j) bh_[j] = (_Float16)p[j];
                HBh[kk] = bh_;
            }
        }
    }

    // ---- per-lane scalar weights / biases (prescaled) ----
    const float wir0 = LOG2E*Wih[(0*64+unit)*3+0], wir1 = LOG2E*Wih[(0*64+unit)*3+1], wir2 = LOG2E*Wih[(0*64+unit)*3+2];
    const float wiu0 = LOG2E*Wih[(1*64+unit)*3+0], wiu1 = LOG2E*Wih[(1*64+unit)*3+1], wiu2 = LOG2E*Wih[(1*64+unit)*3+2];
    const float win0 = 2.f*LOG2E*Wih[(2*64+unit)*3+0], win1 = 2.f*LOG2E*Wih[(2*64+unit)*3+1], win2 = 2.f*LOG2E*Wih[(2*64+unit)*3+2];
    const float br   = LOG2E*(bih[0*64+unit] + bhh[0*64+unit]);
    const float bu   = LOG2E*(bih[1*64+unit] + bhh[1*64+unit]);
    const float bin_ = 2.f*LOG2E*bih[2*64+unit];
    const float bhn  = 2.f*LOG2E*bhh[2*64+unit];
    float bhc = 0.f;
    if (c16 < 3) bhc = bhead[c16];

    // ---- z for the block's 16-elem tile, replicated across all lanes ----
    float zreg[4][3];
    #pragma unroll
    for (int r = 0; r < 4; ++r)
        #pragma unroll
        for (int c = 0; c < 3; ++c)
            zreg[r][c] = z0[(size_t)(blk*MELEM + 4*g + r)*3 + c];

    // ---- persistent traj cursors (designated: wave 0, c16<3) ----
    float* o0 = out; float* o1 = out; float* o2 = out; float* o3 = out;
    if (w == 0 && c16 < 3) {
        size_t e0 = (size_t)(blk*MELEM + 4*g);
        o0 = out + (e0+0)*T3 + c16;
        o1 = out + (e0+1)*T3 + c16;
        o2 = out + (e0+2)*T3 + c16;
        o3 = out + (e0+3)*T3 + c16;
    }
    // t=0 row
    #pragma unroll
    for (int c = 0; c < 3; ++c)
        if (w == 0 && c16 == c) {
            o0[0] = zreg[0][c]; o1[0] = zreg[1][c];
            o2[0] = zreg[2][c]; o3[0] = zreg[3][c];
        }
    if (w == 0 && c16 < 3) { o0 += 3; o1 += 3; o2 += 3; o3 += 3; }  // -> t=1

    // hoisted bpermute byte-addresses
    const int sa0 = (l & 48) << 2;
    const int sa1 = sa0 + 4;
    const int sa2 = sa0 + 8;

    // step-invariant LDS element offsets
    const int adA0 = c16*HS + 8*g;           // A-frag read row
    const int adW  = (4*g)*HS + unit;        // h write base (+ r*HS)

    // ---- zero h buffer 0 (h_0 = 0): 576 dwords ----
    {
        uint* hz = (uint*)&hbuf[0][0];
        for (int i = tid; i < (MELEM*HS)/2; i += 256) hz[i] = 0u;
    }

    float hC[4] = {0.f,0.f,0.f,0.f};

    __syncthreads();

#define GATE(GT, GR, BIAS) do {                                                  \
    f32x4 a1 = {BIAS,BIAS,BIAS,BIAS};                                            \
    a1 = __builtin_amdgcn_mfma_f32_16x16x32_f16(FAh0, WBh[GT][0], a1, 0,0,0);    \
    a1 = __builtin_amdgcn_mfma_f32_16x16x32_f16(FAh1, WBh[GT][1], a1, 0,0,0);    \
    GR = a1;                                                                     \
} while (0)

#define STEP(P, DOZ) do {                                                        \
    f16x8 FAh0 = *(const f16x8*)&hbuf[P][adA0];                                  \
    f16x8 FAh1 = *(const f16x8*)&hbuf[P][adA0 + 32];                             \
    if (DOZ) {                                                                   \
        f32x4 a = {bhc,bhc,bhc,bhc};                                             \
        a = __builtin_amdgcn_mfma_f32_16x16x32_f16(FAh0, HBh[0], a, 0,0,0);      \
        a = __builtin_amdgcn_mfma_f32_16x16x32_f16(FAh1, HBh[1], a, 0,0,0);      \
        _Pragma("unroll")                                                        \
        for (int r = 0; r < 4; ++r) {                                            \
            float fv = a[r];                                                     \
            zreg[r][0] = __builtin_fmaf(dtv, bpermf(sa0, fv), zreg[r][0]);       \
            zreg[r][1] = __builtin_fmaf(dtv, bpermf(sa1, fv), zreg[r][1]);       \
            zreg[r][2] = __builtin_fmaf(dtv, bpermf(sa2, fv), zreg[r][2]);       \
        }                                                                        \
        _Pragma("unroll")                                                        \
        for (int c = 0; c < 3; ++c)                                              \
            if (w == 0 && c16 == c) {                                            \
                o0[0] = zreg[0][c]; o1[0] = zreg[1][c];                          \
                o2[0] = zreg[2][c]; o3[0] = zreg[3][c];                          \
            }                                                                    \
        if (w == 0 && c16 < 3) { o0 += 3; o1 += 3; o2 += 3; o3 += 3; }           \
    }                                                                            \
    f32x4 gr0, gr1, gr2;                                                         \
    GATE(0, gr0, br); GATE(1, gr1, bu); GATE(2, gr2, bhn);                       \
    _Pragma("unroll")                                                            \
    for (int r = 0; r < 4; ++r) {                                                \
        float z0v = zreg[r][0], z1v = zreg[r][1], z2v = zreg[r][2];              \
        float ar  = __builtin_fmaf(wir0, z0v, __builtin_fmaf(wir1, z1v,          \
                    __builtin_fmaf(wir2, z2v, gr0[r])));                         \
        float au  = __builtin_fmaf(wiu0, z0v, __builtin_fmaf(wiu1, z1v,          \
                    __builtin_fmaf(wiu2, z2v, gr1[r])));                         \
        float ain = __builtin_fmaf(win0, z0v, __builtin_fmaf(win1, z1v,          \
                    __builtin_fmaf(win2, z2v, bin_)));                           \
        float rg  = __builtin_amdgcn_rcpf(1.f + __builtin_amdgcn_exp2f(-ar));    \
        float ug_ = __builtin_amdgcn_rcpf(1.f + __builtin_amdgcn_exp2f(-au));    \
        float xs  = __builtin_fmaf(rg, gr2[r], ain);                             \
        float ng  = __builtin_fmaf(-2.f,                                         \
            __builtin_amdgcn_rcpf(1.f + __builtin_amdgcn_exp2f(xs)), 1.f);       \
        float hn  = __builtin_fmaf(ug_, hC[r] - ng, ng);                         \
        hC[r] = hn;                                                              \
        hbuf[(P)^1][adW + r*HS] = (_Float16)hn;                                  \
    }                                                                            \
    LDS_BARRIER();                                                               \
} while (0)

    // ---- main loop: peel t=0, then pairs (compile-time ping-pong) ----
    STEP(0, false);
    int t = 1;
    for (; t + 1 < nsteps; t += 2) {
        STEP(1, true);
        STEP(0, true);
    }
    if (t < nsteps) { STEP(1, true); ++t; }

    // ---- epilogue: z(nsteps) from head over h(nsteps) ----
    {
        const int P = nsteps & 1;
        f16x8 FAh0 = *(const f16x8*)&hbuf[P][adA0];
        f16x8 FAh1 = *(const f16x8*)&hbuf[P][adA0 + 32];
        f32x4 a = {bhc,bhc,bhc,bhc};
        a = __builtin_amdgcn_mfma_f32_16x16x32_f16(FAh0, HBh[0], a, 0,0,0);
        a = __builtin_amdgcn_mfma_f32_16x16x32_f16(FAh1, HBh[1], a, 0,0,0);
        #pragma unroll
        for (int r = 0; r < 4; ++r) {
            float fv = a[r];
            zreg[r][0] = __builtin_fmaf(dtv, bpermf(sa0, fv), zreg[r][0]);
            zreg[r][1] = __builtin_fmaf(dtv, bpermf(sa1, fv), zreg[r][1]);
            zreg[r][2] = __builtin_fmaf(dtv, bpermf(sa2, fv), zreg[r][2]);
        }
        #pragma unroll
        for (int c = 0; c < 3; ++c)
            if (w == 0 && c16 == c) {
                o0[0] = zreg[0][c]; o1[0] = zreg[1][c];
                o2[0] = zreg[2][c]; o3[0] = zreg[3][c];
            }
    }
#undef STEP
#undef GATE
}

extern "C" void kernel_launch(void* const* d_in, const int* in_sizes, int n_in,
                              void* d_out, int out_size, void* d_ws, size_t ws_size,
                              hipStream_t stream) {
    const float* z0    = (const float*)d_in[0];
    const float* dtp   = (const float*)d_in[1];
    const int*   steps = (const int*)  d_in[2];
    const float* Wih   = (const float*)d_in[3];
    const float* Whh   = (const float*)d_in[4];
    const float* bih   = (const float*)d_in[5];
    const float* bhh   = (const float*)d_in[6];
    const float* Whead = (const float*)d_in[7];
    const float* bhead = (const float*)d_in[8];
    float* out = (float*)d_out;

    const int B = in_sizes[0] / 3;          // 16384
    const int nblk = B / MELEM;             // 1024 blocks x 256 threads

    hipLaunchKernelGGL(gru_mfma_kernel, dim3(nblk), dim3(256), 0, stream,
                       z0, dtp, steps, Wih, Whh, bih, bhh, Whead, bhead, out);
}

// Round 21
// 2434.614 us; speedup vs baseline: 2.1508x; 1.0729x over previous
//
#include <hip/hip_runtime.h>

typedef _Float16 f16x8 __attribute__((ext_vector_type(8)));
typedef float f32x4 __attribute__((ext_vector_type(4)));
typedef float f32x2 __attribute__((ext_vector_type(2)));

#define LOG2E 1.44269504088896340736f
#define MELEM 16          // batch elems per block (1 M-tile of 16)
#define HS 72             // f16 stride of h LDS rows (16B-aligned, bank-spread)

#define EF2(A,B,C) __builtin_elementwise_fma((A),(B),(C))
#define SPL(S) ((f32x2){(S),(S)})

__device__ __forceinline__ float bpermf(int sa, float v) {
    return __builtin_bit_cast(float,
        __builtin_amdgcn_ds_bpermute(sa, __builtin_bit_cast(int, v)));
}

// barrier that waits ONLY on LDS (lgkm), not on in-flight global traj stores
#define LDS_BARRIER() asm volatile("s_waitcnt lgkmcnt(0)\n\ts_barrier" ::: "memory")

// R20 structure (fp16 weights, fp16 h, fp32 z); gate-finish + z-update math
// packed into float2 pairs so the backend can emit v_pk_fma_f32 (dual fp32).
__global__ __launch_bounds__(256, 2)
void gru_mfma_kernel(const float* __restrict__ z0,
                     const float* __restrict__ dtp,
                     const int* __restrict__ stepsp,
                     const float* __restrict__ Wih,
                     const float* __restrict__ Whh,
                     const float* __restrict__ bih,
                     const float* __restrict__ bhh,
                     const float* __restrict__ Whead,
                     const float* __restrict__ bhead,
                     float* __restrict__ out)
{
    // [pingpong][elem*HS + unit], plain fp16 h  (4608 B)
    __shared__ _Float16 hbuf[2][MELEM*HS];

    const int tid = threadIdx.x;
    const int w   = tid >> 6;       // wave 0..3 = unit group
    const int l   = tid & 63;
    const int c16 = l & 15;
    const int g   = l >> 4;         // 0..3
    const int unit = 16*w + c16;

    const float dtv = dtp[0];
    const int nsteps = stepsp[0];
    const size_t T3 = (size_t)(nsteps + 1) * 3;
    const long blk = blockIdx.x;

    // ---- B-fragments of W_hh: plain fp16, LOG2E-prescaled ----
    f16x8 WBh[3][2];
    #pragma unroll
    for (int gate = 0; gate < 3; ++gate) {
        const float gs = (gate == 2) ? 2.f*LOG2E : LOG2E;
        const float* row = Whh + (size_t)(gate*64 + unit) * 64;
        #pragma unroll
        for (int kk = 0; kk < 2; ++kk) {
            const float* p = row + 32*kk + 8*g;
            f16x8 bh_;
            #pragma unroll
            for (int j = 0; j < 8; ++j) bh_[j] = (_Float16)(gs * p[j]);
            WBh[gate][kk] = bh_;
        }
    }
    // ---- head B-fragments, plain fp16 (cols >= 3 zero) ----
    f16x8 HBh[2];
    {
        f16x8 zf = {0,0,0,0,0,0,0,0};
        HBh[0]=zf; HBh[1]=zf;
        if (c16 < 3) {
            #pragma unroll
            for (int kk = 0; kk < 2; ++kk) {
                const float* p = Whead + (size_t)c16*64 + 32*kk + 8*g;
                f16x8 bh_;
                #pragma unroll
                for (int j = 0; j < 8; ++j) bh_[j] = (_Float16)p[j];
                HBh[kk] = bh_;
            }
        }
    }

    // ---- per-lane scalar weights / biases (prescaled) ----
    const float wir0 = LOG2E*Wih[(0*64+unit)*3+0], wir1 = LOG2E*Wih[(0*64+unit)*3+1], wir2 = LOG2E*Wih[(0*64+unit)*3+2];
    const float wiu0 = LOG2E*Wih[(1*64+unit)*3+0], wiu1 = LOG2E*Wih[(1*64+unit)*3+1], wiu2 = LOG2E*Wih[(1*64+unit)*3+2];
    const float win0 = 2.f*LOG2E*Wih[(2*64+unit)*3+0], win1 = 2.f*LOG2E*Wih[(2*64+unit)*3+1], win2 = 2.f*LOG2E*Wih[(2*64+unit)*3+2];
    const float br   = LOG2E*(bih[0*64+unit] + bhh[0*64+unit]);
    const float bu   = LOG2E*(bih[1*64+unit] + bhh[1*64+unit]);
    const float bin_ = 2.f*LOG2E*bih[2*64+unit];
    const float bhn  = 2.f*LOG2E*bhh[2*64+unit];
    float bhc = 0.f;
    if (c16 < 3) bhc = bhead[c16];

    // ---- z pairs: zp01[c] = {z[elem 4g+0][c], z[elem 4g+1][c]}, zp23 = r=2,3 ----
    f32x2 zp01[3], zp23[3];
    #pragma unroll
    for (int c = 0; c < 3; ++c) {
        size_t e0 = (size_t)(blk*MELEM + 4*g);
        zp01[c].x = z0[(e0+0)*3 + c]; zp01[c].y = z0[(e0+1)*3 + c];
        zp23[c].x = z0[(e0+2)*3 + c]; zp23[c].y = z0[(e0+3)*3 + c];
    }

    // ---- persistent traj cursors (designated: wave 0, c16<3) ----
    float* o0 = out; float* o1 = out; float* o2 = out; float* o3 = out;
    if (w == 0 && c16 < 3) {
        size_t e0 = (size_t)(blk*MELEM + 4*g);
        o0 = out + (e0+0)*T3 + c16;
        o1 = out + (e0+1)*T3 + c16;
        o2 = out + (e0+2)*T3 + c16;
        o3 = out + (e0+3)*T3 + c16;
    }
    // t=0 row
    #pragma unroll
    for (int c = 0; c < 3; ++c)
        if (w == 0 && c16 == c) {
            o0[0] = zp01[c].x; o1[0] = zp01[c].y;
            o2[0] = zp23[c].x; o3[0] = zp23[c].y;
        }
    if (w == 0 && c16 < 3) { o0 += 3; o1 += 3; o2 += 3; o3 += 3; }  // -> t=1

    // hoisted bpermute byte-addresses
    const int sa0 = (l & 48) << 2;
    const int sa1 = sa0 + 4;
    const int sa2 = sa0 + 8;

    // step-invariant LDS element offsets
    const int adA0 = c16*HS + 8*g;           // A-frag read row
    const int adW  = (4*g)*HS + unit;        // h write base (+ r*HS)

    // ---- zero h buffer 0 (h_0 = 0): 576 dwords ----
    {
        uint* hz = (uint*)&hbuf[0][0];
        for (int i = tid; i < (MELEM*HS)/2; i += 256) hz[i] = 0u;
    }

    f32x2 hp01 = {0.f, 0.f}, hp23 = {0.f, 0.f};

    __syncthreads();

#define GATE(GT, GR, BIAS) do {                                                  \
    f32x4 a1 = {BIAS,BIAS,BIAS,BIAS};                                            \
    a1 = __builtin_amdgcn_mfma_f32_16x16x32_f16(FAh0, WBh[GT][0], a1, 0,0,0);    \
    a1 = __builtin_amdgcn_mfma_f32_16x16x32_f16(FAh1, WBh[GT][1], a1, 0,0,0);    \
    GR = a1;                                                                     \
} while (0)

// packed pair finish: ZP/HP are f32x2[3]/f32x2 for rows (R0, R0+1)
#define FINP(P, ZP, HP, G0, G1, G2, R0) do {                                     \
    f32x2 ar = EF2(SPL(wir0), ZP[0], EF2(SPL(wir1), ZP[1],                       \
               EF2(SPL(wir2), ZP[2], G0)));                                      \
    f32x2 au = EF2(SPL(wiu0), ZP[0], EF2(SPL(wiu1), ZP[1],                       \
               EF2(SPL(wiu2), ZP[2], G1)));                                      \
    f32x2 ai = EF2(SPL(win0), ZP[0], EF2(SPL(win1), ZP[1],                       \
               EF2(SPL(win2), ZP[2], SPL(bin_))));                               \
    f32x2 one = {1.f, 1.f};                                                      \
    f32x2 er; er.x = __builtin_amdgcn_exp2f(-ar.x); er.y = __builtin_amdgcn_exp2f(-ar.y); \
    f32x2 eu; eu.x = __builtin_amdgcn_exp2f(-au.x); eu.y = __builtin_amdgcn_exp2f(-au.y); \
    er = er + one; eu = eu + one;                                                \
    f32x2 rg; rg.x = __builtin_amdgcn_rcpf(er.x); rg.y = __builtin_amdgcn_rcpf(er.y); \
    f32x2 ug; ug.x = __builtin_amdgcn_rcpf(eu.x); ug.y = __builtin_amdgcn_rcpf(eu.y); \
    f32x2 xs = EF2(rg, G2, ai);                                                  \
    f32x2 en; en.x = __builtin_amdgcn_exp2f(xs.x); en.y = __builtin_amdgcn_exp2f(xs.y); \
    en = en + one;                                                               \
    f32x2 rn; rn.x = __builtin_amdgcn_rcpf(en.x); rn.y = __builtin_amdgcn_rcpf(en.y); \
    f32x2 ng = EF2(SPL(-2.f), rn, one);                                          \
    f32x2 hn = EF2(ug, HP - ng, ng);                                             \
    HP = hn;                                                                     \
    hbuf[(P)^1][adW + (R0+0)*HS] = (_Float16)hn.x;                               \
    hbuf[(P)^1][adW + (R0+1)*HS] = (_Float16)hn.y;                               \
} while (0)

#define STEP(P, DOZ) do {                                                        \
    f16x8 FAh0 = *(const f16x8*)&hbuf[P][adA0];                                  \
    f16x8 FAh1 = *(const f16x8*)&hbuf[P][adA0 + 32];                             \
    if (DOZ) {                                                                   \
        f32x4 a = {bhc,bhc,bhc,bhc};                                             \
        a = __builtin_amdgcn_mfma_f32_16x16x32_f16(FAh0, HBh[0], a, 0,0,0);      \
        a = __builtin_amdgcn_mfma_f32_16x16x32_f16(FAh1, HBh[1], a, 0,0,0);      \
        f32x2 dt2 = SPL(dtv);                                                    \
        f32x2 b01, b23;                                                          \
        b01.x = bpermf(sa0, a[0]); b01.y = bpermf(sa0, a[1]);                    \
        b23.x = bpermf(sa0, a[2]); b23.y = bpermf(sa0, a[3]);                    \
        zp01[0] = EF2(dt2, b01, zp01[0]); zp23[0] = EF2(dt2, b23, zp23[0]);      \
        b01.x = bpermf(sa1, a[0]); b01.y = bpermf(sa1, a[1]);                    \
        b23.x = bpermf(sa1, a[2]); b23.y = bpermf(sa1, a[3]);                    \
        zp01[1] = EF2(dt2, b01, zp01[1]); zp23[1] = EF2(dt2, b23, zp23[1]);      \
        b01.x = bpermf(sa2, a[0]); b01.y = bpermf(sa2, a[1]);                    \
        b23.x = bpermf(sa2, a[2]); b23.y = bpermf(sa2, a[3]);                    \
        zp01[2] = EF2(dt2, b01, zp01[2]); zp23[2] = EF2(dt2, b23, zp23[2]);      \
        _Pragma("unroll")                                                        \
        for (int c = 0; c < 3; ++c)                                              \
            if (w == 0 && c16 == c) {                                            \
                o0[0] = zp01[c].x; o1[0] = zp01[c].y;                            \
                o2[0] = zp23[c].x; o3[0] = zp23[c].y;                            \
            }                                                                    \
        if (w == 0 && c16 < 3) { o0 += 3; o1 += 3; o2 += 3; o3 += 3; }           \
    }                                                                            \
    f32x4 gr0, gr1, gr2;                                                         \
    GATE(0, gr0, br); GATE(1, gr1, bu); GATE(2, gr2, bhn);                       \
    {                                                                            \
        f32x2 g0lo = __builtin_shufflevector(gr0, gr0, 0, 1);                    \
        f32x2 g1lo = __builtin_shufflevector(gr1, gr1, 0, 1);                    \
        f32x2 g2lo = __builtin_shufflevector(gr2, gr2, 0, 1);                    \
        FINP(P, zp01, hp01, g0lo, g1lo, g2lo, 0);                                \
        f32x2 g0hi = __builtin_shufflevector(gr0, gr0, 2, 3);                    \
        f32x2 g1hi = __builtin_shufflevector(gr1, gr1, 2, 3);                    \
        f32x2 g2hi = __builtin_shufflevector(gr2, gr2, 2, 3);                    \
        FINP(P, zp23, hp23, g0hi, g1hi, g2hi, 2);                                \
    }                                                                            \
    LDS_BARRIER();                                                               \
} while (0)

    // ---- main loop: peel t=0, then pairs (compile-time ping-pong) ----
    STEP(0, false);
    int t = 1;
    for (; t + 1 < nsteps; t += 2) {
        STEP(1, true);
        STEP(0, true);
    }
    if (t < nsteps) { STEP(1, true); ++t; }

    // ---- epilogue: z(nsteps) from head over h(nsteps) ----
    {
        const int P = nsteps & 1;
        f16x8 FAh0 = *(const f16x8*)&hbuf[P][adA0];
        f16x8 FAh1 = *(const f16x8*)&hbuf[P][adA0 + 32];
        f32x4 a = {bhc,bhc,bhc,bhc};
        a = __builtin_amdgcn_mfma_f32_16x16x32_f16(FAh0, HBh[0], a, 0,0,0);
        a = __builtin_amdgcn_mfma_f32_16x16x32_f16(FAh1, HBh[1], a, 0,0,0);
        f32x2 dt2 = SPL(dtv);
        f32x2 b01, b23;
        b01.x = bpermf(sa0, a[0]); b01.y = bpermf(sa0, a[1]);
        b23.x = bpermf(sa0, a[2]); b23.y = bpermf(sa0, a[3]);
        zp01[0] = EF2(dt2, b01, zp01[0]); zp23[0] = EF2(dt2, b23, zp23[0]);
        b01.x = bpermf(sa1, a[0]); b01.y = bpermf(sa1, a[1]);
        b23.x = bpermf(sa1, a[2]); b23.y = bpermf(sa1, a[3]);
        zp01[1] = EF2(dt2, b01, zp01[1]); zp23[1] = EF2(dt2, b23, zp23[1]);
        b01.x = bpermf(sa2, a[0]); b01.y = bpermf(sa2, a[1]);
        b23.x = bpermf(sa2, a[2]); b23.y = bpermf(sa2, a[3]);
        zp01[2] = EF2(dt2, b01, zp01[2]); zp23[2] = EF2(dt2, b23, zp23[2]);
        #pragma unroll
        for (int c = 0; c < 3; ++c)
            if (w == 0 && c16 == c) {
                o0[0] = zp01[c].x; o1[0] = zp01[c].y;
                o2[0] = zp23[c].x; o3[0] = zp23[c].y;
            }
    }
#undef STEP
#undef FINP
#undef GATE
}

extern "C" void kernel_launch(void* const* d_in, const int* in_sizes, int n_in,
                              void* d_out, int out_size, void* d_ws, size_t ws_size,
                              hipStream_t stream) {
    const float* z0    = (const float*)d_in[0];
    const float* dtp   = (const float*)d_in[1];
    const int*   steps = (const int*)  d_in[2];
    const float* Wih   = (const float*)d_in[3];
    const float* Whh   = (const float*)d_in[4];
    const float* bih   = (const float*)d_in[5];
    const float* bhh   = (const float*)d_in[6];
    const float* Whead = (const float*)d_in[7];
    const float* bhead = (const float*)d_in[8];
    float* out = (float*)d_out;

    const int B = in_sizes[0] / 3;          // 16384
    const int nblk = B / MELEM;             // 1024 blocks x 256 threads

    hipLaunchKernelGGL(gru_mfma_kernel, dim3(nblk), dim3(256), 0, stream,
                       z0, dtp, steps, Wih, Whh, bih, bhh, Whead, bhead, out);
}